// Round 1
// baseline (394.515 us; speedup 1.0000x reference)
//
#include <hip/hip_runtime.h>

// DerivNet2D fused MLP + forward-mode derivatives.
// GEMM formulation: A[96 rows = {z1, d1*W1c0, d1*W1c1} x 32 samples][K=1024] @ W2^T -> [96][512]
// per workgroup, MFMA 32x32x16 bf16, fp32 accum. Epilogue reduces over N=512 with W3.

#define NXS    65536
#define SB     32
#define NBLK   2048        // NXS / SB
#define KTOT   1024
#define KSTEPS 16          // KTOT / 64

typedef __attribute__((ext_vector_type(8)))  short bh8_t;   // 8 x bf16 (4 VGPR)
typedef __attribute__((ext_vector_type(16))) float fx16_t;  // 32x32 accumulator
typedef unsigned int u32;

// LDS byte layout: A tiles [96][64]bf16 = 12KB x2, B tiles [512][64]bf16 = 64KB x2
#define LDS_A0 0
#define LDS_A1 12288
#define LDS_B0 24576
#define LDS_B1 90112
#define LDS_TOTAL 155648

static __device__ __forceinline__ unsigned short f2bf(float f) {
  u32 u = __builtin_bit_cast(u32, f);
  u += 0x7FFFu + ((u >> 16) & 1u);      // RNE
  return (unsigned short)(u >> 16);
}

static __device__ __forceinline__ float fast_tanh(float h) {
  float e = __expf(2.0f * h);
  return 1.0f - 2.0f / (e + 1.0f);
}

static __device__ __forceinline__ void gload16(const void* g, void* l) {
  __builtin_amdgcn_global_load_lds(
      (const __attribute__((address_space(1))) u32*)g,
      (__attribute__((address_space(3))) u32*)l, 16, 0, 0);
}

// Convert W2 fp32 [512][1024] -> bf16, same row-major layout but with k
// interleaved per 16-block (swap bits 2<->3 of k&15) so one ds_read_b128
// yields a full two-half MFMA fragment {4q+j} U {8+4q+j}.
__global__ void prep_w2(const float* __restrict__ W2, unsigned short* __restrict__ W2p) {
  int gid = (blockIdx.x * 256 + threadIdx.x) * 4;
  float4 v = *(const float4*)(W2 + gid);
  int n  = gid >> 10;
  int k0 = gid & 1023;
  int kl = k0 & 15;                                    // in {0,4,8,12}
  int pos = (kl & 3) | ((kl & 4) << 1) | ((kl & 8) >> 1);  // swap bits 2,3 (involution)
  ushort4 o;
  o.x = f2bf(v.x); o.y = f2bf(v.y); o.z = f2bf(v.z); o.w = f2bf(v.w);
  *(ushort4*)(W2p + (n << 10) + (k0 & ~15) + pos) = o;
}

__global__ __launch_bounds__(1024, 4) void fused_kernel(
    const float* __restrict__ x,  const float* __restrict__ W1,
    const float* __restrict__ b1, const float* __restrict__ b2,
    const float* __restrict__ W3, const float* __restrict__ b3,
    const char* __restrict__ W2p, float* __restrict__ out)
{
  extern __shared__ __attribute__((aligned(16))) char smem[];
  const int tid  = threadIdx.x;
  const int lane = tid & 63;
  const int wave = tid >> 6;        // 0..15, owns N cols [32w, 32w+32)
  const int q    = lane >> 5;       // MFMA lane-half
  const int col  = lane & 31;
  const int s0   = blockIdx.x * SB;

  // B staging: per-lane source pre-swizzle; LDS dest stays linear (rule #21).
  const int srow  = lane >> 3;               // row within 8-row group
  const int sunit = (lane & 7) ^ srow;       // logical 16B unit = phys ^ (n&7)

  // A generation (threads 0..255 = waves 0..3): (sample gs, k-octet gks/gqp)
  const bool genA = (tid < 256);
  int gs = 0, gks = 0, gqp = 0;
  float x0 = 0.f, x1 = 0.f;
  if (genA) {
    gs  = tid >> 3;
    gks = (tid & 7) >> 1;
    gqp = tid & 1;
    const float2 xv = *(const float2*)(x + 2 * (s0 + gs));
    x0 = xv.x; x1 = xv.y;
  }

  const int   n_glob = wave * 32 + col;
  const float b2n = b2[n_glob];
  const float w3n = W3[n_glob];

  fx16_t acc0 = {0,0,0,0,0,0,0,0,0,0,0,0,0,0,0,0};  // h2 band (z1 rows)
  fx16_t acc1 = acc0;                                // g1 band (d1*W1c0)
  fx16_t acc2 = acc0;                                // g2 band (d1*W1c1)

  const int amask = (col & 7) * 16;   // XOR swizzle mask; (n_glob&7)==(col&7) too

  auto stage = [&](int kt, int buf) {
    // B tile: [512 n][64 k] bf16, 64 x global_load_lds_dwordx4 across 16 waves
    char* Bb = smem + (buf ? LDS_B1 : LDS_B0);
    const char* src0 = W2p + srow * 2048 + kt * 128 + sunit * 16;
#pragma unroll
    for (int i = 0; i < 4; ++i) {
      int blk = wave * 4 + i;
      gload16(src0 + blk * (8 * 2048), Bb + blk * 1024);
    }
    // A tile: compute z1 / d1*W1 on the fly, write swizzled+interleaved octets
    if (genA) {
      const int kb = kt * 64 + 16 * gks + 4 * gqp;
      bh8_t vz, va0, va1;
#pragma unroll
      for (int i = 0; i < 8; ++i) {
        int k = kb + (i < 4 ? i : 4 + i);   // {4q'+j} then {8+4q'+j}
        float2 w = *(const float2*)(W1 + 2 * k);
        float h = fmaf(x0, w.x, fmaf(x1, w.y, b1[k]));
        float z = fast_tanh(h);
        float d = 1.f - z * z;
        vz[i]  = (short)f2bf(z);
        va0[i] = (short)f2bf(d * w.x);
        va1[i] = (short)f2bf(d * w.y);
      }
      char* Ab = smem + (buf ? LDS_A1 : LDS_A0);
      const int uoff = ((2 * gks + gqp) ^ (gs & 7)) * 16;
      *(bh8_t*)(Ab + gs * 128 + uoff)        = vz;    // rows 0..31:  z1
      *(bh8_t*)(Ab + (32 + gs) * 128 + uoff) = va0;   // rows 32..63: d1*W1c0
      *(bh8_t*)(Ab + (64 + gs) * 128 + uoff) = va1;   // rows 64..95: d1*W1c1
    }
  };

  stage(0, 0);
  __syncthreads();

  for (int kt = 0; kt < KSTEPS; ++kt) {
    const int cur = kt & 1;
    if (kt + 1 < KSTEPS) stage(kt + 1, cur ^ 1);   // prefetch overlaps MFMAs
    const char* Ab = smem + (cur ? LDS_A1 : LDS_A0);
    const char* Bb = smem + (cur ? LDS_B1 : LDS_B0);
    const int abase = col * 128;
    const int bbase = n_glob * 128;
#pragma unroll
    for (int ks = 0; ks < 4; ++ks) {
      const int uoff = ((2 * ks + q) * 16) ^ amask;
      bh8_t bf  = *(const bh8_t*)(Bb + bbase + uoff);
      bh8_t a0f = *(const bh8_t*)(Ab + abase + uoff);
      bh8_t a1f = *(const bh8_t*)(Ab + abase + 4096 + uoff);
      bh8_t a2f = *(const bh8_t*)(Ab + abase + 8192 + uoff);
      acc0 = __builtin_amdgcn_mfma_f32_32x32x16_bf16(a0f, bf, acc0, 0, 0, 0);
      acc1 = __builtin_amdgcn_mfma_f32_32x32x16_bf16(a1f, bf, acc1, 0, 0, 0);
      acc2 = __builtin_amdgcn_mfma_f32_32x32x16_bf16(a2f, bf, acc2, 0, 0, 0);
    }
    __syncthreads();
  }

  // Epilogue: z2 = tanh(h2+b2), d2 = 1-z2^2; reduce over n with W3.
  float* P = (float*)smem;   // [3][32 samples][16 waves] partials, 6KB
#pragma unroll
  for (int r = 0; r < 16; ++r) {
    const int srow_o = (r & 3) + 8 * (r >> 2) + 4 * q;  // sample index 0..31
    float z2 = fast_tanh(acc0[r] + b2n);
    float d2 = 1.f - z2 * z2;
    float py = w3n * z2;
    float p1 = w3n * d2 * acc1[r];
    float p2 = w3n * d2 * acc2[r];
#pragma unroll
    for (int m = 1; m < 32; m <<= 1) {
      py += __shfl_xor(py, m, 64);
      p1 += __shfl_xor(p1, m, 64);
      p2 += __shfl_xor(p2, m, 64);
    }
    if (col == 0) {
      P[0 * 512 + srow_o * 16 + wave] = py;
      P[1 * 512 + srow_o * 16 + wave] = p1;
      P[2 * 512 + srow_o * 16 + wave] = p2;
    }
  }
  __syncthreads();
  if (tid < 96) {
    const int v = tid >> 5, s = tid & 31;
    float sum = 0.f;
#pragma unroll
    for (int w = 0; w < 16; ++w) sum += P[v * 512 + s * 16 + w];
    const int si = s0 + s;
    if (v == 0)      out[si]           = sum + b3[0];  // y
    else if (v == 2) out[NXS + si]     = sum;          // v1 = dydx2
    else             out[2 * NXS + si] = -sum;         // v2 = -dydx1
  }
}

extern "C" void kernel_launch(void* const* d_in, const int* in_sizes, int n_in,
                              void* d_out, int out_size, void* d_ws, size_t ws_size,
                              hipStream_t stream) {
  const float* x  = (const float*)d_in[0];
  const float* W1 = (const float*)d_in[1];
  const float* b1 = (const float*)d_in[2];
  const float* W2 = (const float*)d_in[3];
  const float* b2 = (const float*)d_in[4];
  const float* W3 = (const float*)d_in[5];
  const float* b3 = (const float*)d_in[6];
  unsigned short* W2p = (unsigned short*)d_ws;   // 1 MB bf16 W2, k-interleaved

  prep_w2<<<512, 256, 0, stream>>>(W2, W2p);

  (void)hipFuncSetAttribute(reinterpret_cast<const void*>(fused_kernel),
                            hipFuncAttributeMaxDynamicSharedMemorySize, 160 * 1024);
  fused_kernel<<<NBLK, 1024, LDS_TOTAL, stream>>>(
      x, W1, b1, b2, W3, b3, (const char*)W2p, (float*)d_out);
}

// Round 2
// 289.035 us; speedup vs baseline: 1.3649x; 1.3649x over previous
//
#include <hip/hip_runtime.h>

// DerivNet2D fused MLP + forward-mode derivatives, v2.
// A[96 = 3 bands x 32 samples][K=1024] @ W2^T[1024][512] with MFMA 32x32x16 bf16.
// A generated on the fly into LDS (double-buffered, 24 KB); B (W2 bf16, 1 MB)
// read per-fragment straight from L2 via a fragment-major prepped layout.
// Block = 256 threads (4 waves), wave owns 128 N-cols (nb=4); 2 blocks/CU.

#define NXS    65536
#define SB     32
#define NBLK   2048        // NXS / SB
#define KSTEPS 16          // K=1024 / 64

typedef __attribute__((ext_vector_type(8)))  short bh8_t;   // 8 x bf16
typedef __attribute__((ext_vector_type(16))) float fx16_t;  // 32x32 accum
typedef unsigned int u32;

static __device__ __forceinline__ unsigned short f2bf(float f) {
  u32 u = __builtin_bit_cast(u32, f);
  u += 0x7FFFu + ((u >> 16) & 1u);      // RNE
  return (unsigned short)(u >> 16);
}

static __device__ __forceinline__ float fast_tanh(float h) {
  float e = __expf(2.0f * h);
  return 1.0f - 2.0f / (e + 1.0f);
}

// W2 fp32 [512][1024] -> fragment-major bf16:
// frag f = ((kblock*16 + nbk)*64 + q*32 + col), 16 bytes each, holding
// W2[n = nbk*32+col][k = 16*kblock + {4q..4q+3, 8+4q..8+4q+3}].
// One wave's global_load_dwordx4 at (kblock, nbk) is then 1 KB contiguous.
__global__ void prep_w2t(const float* __restrict__ W2, bh8_t* __restrict__ W2pT) {
  int f = blockIdx.x * 256 + threadIdx.x;      // 0..65535
  int col = f & 31;
  int q   = (f >> 5) & 1;
  int nbk = (f >> 6) & 15;
  int kb  = f >> 10;
  const float* row = W2 + (nbk * 32 + col) * 1024 + kb * 16 + 4 * q;
  float4 lo = *(const float4*)(row);
  float4 hi = *(const float4*)(row + 8);
  bh8_t o;
  o[0] = (short)f2bf(lo.x); o[1] = (short)f2bf(lo.y);
  o[2] = (short)f2bf(lo.z); o[3] = (short)f2bf(lo.w);
  o[4] = (short)f2bf(hi.x); o[5] = (short)f2bf(hi.y);
  o[6] = (short)f2bf(hi.z); o[7] = (short)f2bf(hi.w);
  W2pT[f] = o;
}

__global__ __launch_bounds__(256, 2) void fused_kernel(
    const float* __restrict__ x,  const float* __restrict__ W1,
    const float* __restrict__ b1, const float* __restrict__ b2,
    const float* __restrict__ W3, const float* __restrict__ b3,
    const bh8_t* __restrict__ Bg, float* __restrict__ out)
{
  __shared__ __attribute__((aligned(16))) char smem[24576 + 1536];
  const int tid  = threadIdx.x;
  const int lane = tid & 63;
  const int wave = tid >> 6;        // 0..3, owns N cols [128w, 128w+128)
  const int q    = lane >> 5;
  const int col  = lane & 31;
  const int s0   = blockIdx.x * SB;

  // A-generation role: all 256 threads; one (sample, 16k-block, half) octet x 3 bands
  const int gs  = tid >> 3;         // sample 0..31
  const int gks = (tid & 7) >> 1;   // 16k block 0..3
  const int gqp = tid & 1;          // half
  const float2 xv = *(const float2*)(x + 2 * (s0 + gs));
  const float x0 = xv.x, x1 = xv.y;

  fx16_t acc[3][4];
#pragma unroll
  for (int b = 0; b < 3; ++b)
#pragma unroll
    for (int nb = 0; nb < 4; ++nb)
#pragma unroll
      for (int r = 0; r < 16; ++r) acc[b][nb][r] = 0.0f;

  const int amask = (col & 7) * 16;   // A-read XOR swizzle (row-dependent)

  auto stageA = [&](int kt, char* Ab) {
    const int kb = kt * 64 + 16 * gks + 4 * gqp;
    bh8_t vz, va0, va1;
#pragma unroll
    for (int i = 0; i < 8; ++i) {
      int k = kb + (i < 4 ? i : 4 + i);     // {4q'+j} then {8+4q'+j}
      float2 w = *(const float2*)(W1 + 2 * k);
      float h = fmaf(x0, w.x, fmaf(x1, w.y, b1[k]));
      float z = fast_tanh(h);
      float d = 1.f - z * z;
      vz[i]  = (short)f2bf(z);
      va0[i] = (short)f2bf(d * w.x);
      va1[i] = (short)f2bf(d * w.y);
    }
    const int uoff = ((2 * gks + gqp) ^ (gs & 7)) * 16;
    *(bh8_t*)(Ab + gs * 128 + uoff)        = vz;    // band 0: z1
    *(bh8_t*)(Ab + (32 + gs) * 128 + uoff) = va0;   // band 1: d1*W1c0
    *(bh8_t*)(Ab + (64 + gs) * 128 + uoff) = va1;   // band 2: d1*W1c1
  };

  stageA(0, smem);
  __syncthreads();

  for (int kt = 0; kt < KSTEPS; ++kt) {
    char* Acur = smem + (kt & 1) * 12288;
    char* Anxt = smem + ((kt + 1) & 1) * 12288;
    if (kt + 1 < KSTEPS) stageA(kt + 1, Anxt);   // VALU covers B-load latency
    const int abase = col * 128;
#pragma unroll
    for (int ks = 0; ks < 4; ++ks) {
      const int uoff = ((2 * ks + q) * 16) ^ amask;
      bh8_t a0 = *(const bh8_t*)(Acur + abase + uoff);
      bh8_t a1 = *(const bh8_t*)(Acur + abase + 4096 + uoff);
      bh8_t a2 = *(const bh8_t*)(Acur + abase + 8192 + uoff);
      const int fb = ((4 * kt + ks) * 16 + wave * 4) * 64 + lane;
      bh8_t bf0 = Bg[fb];
      bh8_t bf1 = Bg[fb + 64];
      bh8_t bf2 = Bg[fb + 128];
      bh8_t bf3 = Bg[fb + 192];
      acc[0][0] = __builtin_amdgcn_mfma_f32_32x32x16_bf16(a0, bf0, acc[0][0], 0, 0, 0);
      acc[1][0] = __builtin_amdgcn_mfma_f32_32x32x16_bf16(a1, bf0, acc[1][0], 0, 0, 0);
      acc[2][0] = __builtin_amdgcn_mfma_f32_32x32x16_bf16(a2, bf0, acc[2][0], 0, 0, 0);
      acc[0][1] = __builtin_amdgcn_mfma_f32_32x32x16_bf16(a0, bf1, acc[0][1], 0, 0, 0);
      acc[1][1] = __builtin_amdgcn_mfma_f32_32x32x16_bf16(a1, bf1, acc[1][1], 0, 0, 0);
      acc[2][1] = __builtin_amdgcn_mfma_f32_32x32x16_bf16(a2, bf1, acc[2][1], 0, 0, 0);
      acc[0][2] = __builtin_amdgcn_mfma_f32_32x32x16_bf16(a0, bf2, acc[0][2], 0, 0, 0);
      acc[1][2] = __builtin_amdgcn_mfma_f32_32x32x16_bf16(a1, bf2, acc[1][2], 0, 0, 0);
      acc[2][2] = __builtin_amdgcn_mfma_f32_32x32x16_bf16(a2, bf2, acc[2][2], 0, 0, 0);
      acc[0][3] = __builtin_amdgcn_mfma_f32_32x32x16_bf16(a0, bf3, acc[0][3], 0, 0, 0);
      acc[1][3] = __builtin_amdgcn_mfma_f32_32x32x16_bf16(a1, bf3, acc[1][3], 0, 0, 0);
      acc[2][3] = __builtin_amdgcn_mfma_f32_32x32x16_bf16(a2, bf3, acc[2][3], 0, 0, 0);
    }
    __syncthreads();
  }

  // Epilogue: z2 = tanh(h2+b2), d2 = 1-z2^2; weighted reduce over n with W3.
  float b2n[4], w3n[4];
#pragma unroll
  for (int nb = 0; nb < 4; ++nb) {
    int n = wave * 128 + nb * 32 + col;
    b2n[nb] = b2[n];
    w3n[nb] = W3[n];
  }
  float* P = (float*)(smem + 24576);   // [3][32 samples][4 waves]
#pragma unroll
  for (int r = 0; r < 16; ++r) {
    const int srow_o = (r & 3) + 8 * (r >> 2) + 4 * q;   // sample 0..31
    float py = 0.f, p1 = 0.f, p2 = 0.f;
#pragma unroll
    for (int nb = 0; nb < 4; ++nb) {
      float z2 = fast_tanh(acc[0][nb][r] + b2n[nb]);
      float d2 = 1.f - z2 * z2;
      py = fmaf(w3n[nb], z2, py);
      p1 = fmaf(w3n[nb] * d2, acc[1][nb][r], p1);
      p2 = fmaf(w3n[nb] * d2, acc[2][nb][r], p2);
    }
#pragma unroll
    for (int m = 1; m < 32; m <<= 1) {
      py += __shfl_xor(py, m, 64);
      p1 += __shfl_xor(p1, m, 64);
      p2 += __shfl_xor(p2, m, 64);
    }
    if (col == 0) {
      P[0 * 128 + srow_o * 4 + wave] = py;
      P[1 * 128 + srow_o * 4 + wave] = p1;
      P[2 * 128 + srow_o * 4 + wave] = p2;
    }
  }
  __syncthreads();
  if (tid < 96) {
    const int v = tid >> 5, s = tid & 31;
    const float* Pv = P + v * 128 + s * 4;
    float sum = Pv[0] + Pv[1] + Pv[2] + Pv[3];
    const int si = s0 + s;
    if (v == 0)      out[si]           = sum + b3[0];  // y
    else if (v == 2) out[NXS + si]     = sum;          // v1 = dydx2
    else             out[2 * NXS + si] = -sum;         // v2 = -dydx1
  }
}

extern "C" void kernel_launch(void* const* d_in, const int* in_sizes, int n_in,
                              void* d_out, int out_size, void* d_ws, size_t ws_size,
                              hipStream_t stream) {
  const float* x  = (const float*)d_in[0];
  const float* W1 = (const float*)d_in[1];
  const float* b1 = (const float*)d_in[2];
  const float* W2 = (const float*)d_in[3];
  const float* b2 = (const float*)d_in[4];
  const float* W3 = (const float*)d_in[5];
  const float* b3 = (const float*)d_in[6];
  bh8_t* W2pT = (bh8_t*)d_ws;    // 1 MB fragment-major bf16 W2

  prep_w2t<<<256, 256, 0, stream>>>(W2, W2pT);
  fused_kernel<<<NBLK, 256, 0, stream>>>(
      x, W1, b1, b2, W3, b3, (const bh8_t*)W2pT, (float*)d_out);
}